// Round 15
// baseline (1879.685 us; speedup 1.0000x reference)
//
#include <hip/hip_runtime.h>
#include <math.h>

// LSTM: B=128, T=256, D=256, H=1024, C=10
// Round 16: RESUBMIT of Round 15 (container infra failure, kernel never ran).
//   2 blocks/CU — desynchronized phase overlap.
//   R14 (1757us, best): 1024-thr blocks, 4-way K-split, 4 waves/SIMD. MFMA
//   is ~3% of the 6.6us step; the rest is latency phases (launch, staging,
//   K-loop L2 latency, barrier+combine tail) all locked to ONE barrier
//   domain per CU. This round: grid (64,8) = 512 blocks of 512 thr =
//   2 independent blocks/CU. When one block stages or waits at a barrier,
//   the other's K-loop keeps the CU busy. Per-CU totals per step are
//   IDENTICAL to R14 (2x40KB staging, 2x160KB B, 320 MFMA) — only the
//   synchronization topology changes.
//   - Block = 16 rows x 16 cols x 4 gates; waves = 4 gates x 2 K-halves
//     (R13-proven split); each wave ONE B stream (ct = g*64 + bx), 20 MFMA.
//   - Staging bit-identical to R13 (5 iters x 512 thr, same swzb).
//   - Combine = R13's proven single-phase pLds0/pLds1, ONE barrier.
//   - Cell update tid<256 (256 units), c-prefetch guarded.
//   - __launch_bounds__(512,4): 4 waves/SIMD -> 128-VGPR cap; demand ~80.
//   LDS 48.7KB/block -> 97.4KB for 2 blocks < 160KB.
// Workspace layout (28,311,552 B total):
//   [0)          Wpack  bf16  10,485,760 B
//   [10485760)   xT     bf16  16,777,216 B   ([T][B][D], x transposed+cast)
//   [27262976)   h0     bf16     262,144 B
//   [27525120)   h1     bf16     262,144 B
//   [27787264)   c      fp32     524,288 B

#define BB 128
#define TT 256
#define DD 256
#define HH 1024
#define NKT 40   // 1280 / 32 k-tiles
#define KHT 20   // k-tiles per K-half wave
#define PFA 4    // A-fragment prefetch depth
#define PFB 5    // B-fragment prefetch depth

typedef __bf16 bf16x8 __attribute__((ext_vector_type(8)));
typedef float  f32x4  __attribute__((ext_vector_type(4)));
typedef unsigned short u16;
typedef u16 u16x8 __attribute__((ext_vector_type(8)));

__device__ __forceinline__ u16 f2bf(float f){
  unsigned u = __builtin_bit_cast(unsigned, f);
  u += 0x7fffu + ((u >> 16) & 1u);            // round-to-nearest-even
  return (u16)(u >> 16);
}
__device__ __forceinline__ float bf2f(u16 b){
  unsigned u = ((unsigned)b) << 16;
  return __builtin_bit_cast(float, u);
}
__device__ __forceinline__ float sigm(float x){
  return 1.f / (1.f + __expf(-x));            // R3/R4/R11-proven numerics
}
__device__ __forceinline__ float tanh_fast(float x){
  return 2.f / (1.f + __expf(-2.f * x)) - 1.f;
}
// As4 slot bits: m=[0:3], q=[4:5], kt=[6:11]. R11-proven involution:
// staging wave's 8 consecutive lanes -> 8 distinct bank groups.
__device__ __forceinline__ int swzb(int slot){
  return slot ^ ((slot >> 6) & 7) ^ (((slot >> 4) & 3) << 1);
}

// ---- pack weights into MFMA B-fragment order -------------------------------
// Wpack[ct][kt][lane][j]: ct in [0,256) covers gate-cols [ct*16, ct*16+16)
// (col = gate*1024 + n); element = W[k = kt*32 + (lane>>4)*8 + j][col = ct*16 + (lane&15)]
__global__ void prep_wpack(const float* __restrict__ Wfx, const float* __restrict__ Wix,
                           const float* __restrict__ Wgx, const float* __restrict__ Wox,
                           const float* __restrict__ Wfh, const float* __restrict__ Wih,
                           const float* __restrict__ Wgh, const float* __restrict__ Woh,
                           u16* __restrict__ Wpack){
  int id = blockIdx.x * 256 + threadIdx.x;    // [0, 655360)
  int lane = id & 63;
  int kt = (id >> 6) % NKT;
  int ct = id / (64 * NKT);
  int col = ct * 16 + (lane & 15);
  int g = col >> 10, n = col & 1023;
  int kbase = kt * 32 + (lane >> 4) * 8;
  const float* Wx = (g==0) ? Wfx : (g==1) ? Wix : (g==2) ? Wgx : Wox;
  const float* Wh = (g==0) ? Wfh : (g==1) ? Wih : (g==2) ? Wgh : Woh;
  u16x8 v;
  #pragma unroll
  for (int j = 0; j < 8; ++j){
    int k = kbase + j;
    float f = (k < DD) ? Wx[k * HH + n] : Wh[(k - DD) * HH + n];
    v[j] = f2bf(f);
  }
  *(u16x8*)(Wpack + (size_t)id * 8) = v;      // dst index == id (by construction)
}

// ---- transpose+cast x: xT[t][b][d] = bf16(x[b][t][d]) ----------------------
__global__ void prep_xT(const float* __restrict__ x, u16* __restrict__ xT){
  int id = blockIdx.x * 256 + threadIdx.x;    // [0, 1048576), 8 elems each
  int t = id >> 12;
  int b = (id >> 5) & 127;
  int d0 = (id & 31) * 8;
  const float* src = x + ((size_t)b * TT + t) * DD + d0;
  u16x8 v;
  #pragma unroll
  for (int j = 0; j < 8; ++j) v[j] = f2bf(src[j]);
  *(u16x8*)(xT + (size_t)id * 8) = v;
}

// ---- one LSTM time step: GEMM (bf16 MFMA) + gate activations + state update
// Block: 16 rows x 16 cols x 4 gates, 512 thr; 2 blocks/CU.
// Waves: g = w&3, kh = w>>2 (R13 split); each wave ONE B stream, 20 MFMA.
__global__ __launch_bounds__(512, 4) void lstm_step(
    const u16* __restrict__ xTt,   // [128][256] bf16 (t-slice of xT)
    const u16* __restrict__ Wpack,
    const u16* __restrict__ hin,   // [128][1024] bf16
    u16* __restrict__ hout,        // [128][1024] bf16
    float* __restrict__ cbuf,      // [128][1024] fp32
    const float* __restrict__ bfv, const float* __restrict__ biv,
    const float* __restrict__ bgv, const float* __restrict__ bov){
  __shared__ u16x8 As4[NKT * 64];  // 40 KB: A tile, fragment order, swizzled
  __shared__ float pLds0[16][68];  // kh=0 partials (+bias), 4.25 KB
  __shared__ float pLds1[16][68];  // kh=1 partials, 4.25 KB
  const int tid = threadIdx.x;
  const int bx = blockIdx.x;       // n-tile [0,64)
  const int n0 = bx * 16;          // hidden-unit tile (16 cols)
  const int m0 = blockIdx.y * 16;  // batch-row tile

  // cell-update ownership fixed by tid (tid<256) -> prefetch c-state NOW
  const int crow = tid >> 4, cnn = tid & 15;
  const int gi = (m0 + (crow & 15)) * HH + n0 + cnn;
  float cprev = 0.f;
  if (tid < 256) cprev = cbuf[gi];

  const int w = tid >> 6, lane = tid & 63, cr = lane & 15, q4 = lane >> 4;
  const int g  = w & 3;            // gate
  const int kh = w >> 2;           // K-half: kt in [kh*20, kh*20+20)
  const int ktBeg = kh * KHT;

  // ONE B fragment stream per wave: ct = g*64 + bx (gate g, cols n0..n0+15).
  // Prologue loads issued BEFORE staging so L2 latency hides under staging.
  const u16x8* wq = (const u16x8*)Wpack + (size_t)(g * 64 + bx) * NKT * 64 + lane;
  u16x8 aP[PFA], bP[PFB];
  #pragma unroll
  for (int i = 0; i < PFB; ++i) bP[i] = wq[(size_t)(ktBeg + i) * 64];

  // Stage A = [x_t rows | h rows] (R13-identical: 5 iters x 512 thr).
  // chunk ch -> row m = ch/160, k0 = (ch%160)*8 ; slot = kt*64 + 16*q + m
  #pragma unroll
  for (int it = 0; it < 5; ++it){
    int ch = tid + it * 512;
    int m = ch / 160;
    int k0 = (ch - m * 160) * 8;
    const u16* src = (k0 < DD) ? (xTt + (m0 + m) * DD + k0)
                               : (hin + (m0 + m) * HH + (k0 - DD));
    u16x8 val = *(const u16x8*)src;
    int kt = k0 >> 5, q = (k0 >> 3) & 3;
    As4[swzb(kt * 64 + 16 * q + m)] = val;
  }
  __syncthreads();

  #pragma unroll
  for (int i = 0; i < PFA; ++i) aP[i] = As4[swzb((ktBeg + i) * 64 + lane)];

  f32x4 acc = {0.f, 0.f, 0.f, 0.f};
  #pragma unroll
  for (int kt = 0; kt < KHT; ++kt){
    u16x8 ac = aP[kt % PFA], b = bP[kt % PFB];
    if (kt + PFA < KHT)
      aP[kt % PFA] = As4[swzb((ktBeg + kt + PFA) * 64 + lane)];
    if (kt + PFB < KHT)
      bP[kt % PFB] = wq[(size_t)(ktBeg + kt + PFB) * 64];
    acc = __builtin_amdgcn_mfma_f32_16x16x32_bf16(__builtin_bit_cast(bf16x8, ac),
            __builtin_bit_cast(bf16x8, b), acc, 0, 0, 0);
  }

  // single-phase combine (R13-proven; C/D layout: col=cr, row=q4*4+r):
  // kh=0 writes acc+bias -> pLds0, kh=1 raw acc -> pLds1, ONE barrier.
  if (!kh){
    const float* bptr = (g==0) ? bfv : (g==1) ? biv : (g==2) ? bgv : bov;
    const float bias = bptr[n0 + cr];
    #pragma unroll
    for (int r = 0; r < 4; ++r)
      pLds0[q4 * 4 + r][g * 16 + cr] = acc[r] + bias;
  } else {
    #pragma unroll
    for (int r = 0; r < 4; ++r)
      pLds1[q4 * 4 + r][g * 16 + cr] = acc[r];
  }
  __syncthreads();

  // fused LSTM cell update: 256 (row, hidden) units, tid<256
  if (tid < 256){
    float fp = pLds0[crow][cnn]      + pLds1[crow][cnn];
    float ip = pLds0[crow][16 + cnn] + pLds1[crow][16 + cnn];
    float gp = pLds0[crow][32 + cnn] + pLds1[crow][32 + cnn];
    float op = pLds0[crow][48 + cnn] + pLds1[crow][48 + cnn];
    float fs = sigm(fp);
    float is = sigm(ip);
    float gs = tanh_fast(gp);
    float os = sigm(op);
    float cn = gs * is + cprev * fs;
    cbuf[gi] = cn;
    hout[gi] = f2bf(tanh_fast(cn) * os);
  }
}

// ---- out[b][c] = h_T[b] . Wph[:,c] + bp[c] ---------------------------------
__global__ void final_proj(const u16* __restrict__ h, const float* __restrict__ Wph,
                           const float* __restrict__ bp, float* __restrict__ out){
  __shared__ float red[10][256];
  int b = blockIdx.x, tid = threadIdx.x;
  float p[10];
  #pragma unroll
  for (int c = 0; c < 10; ++c) p[c] = 0.f;
  for (int k = tid; k < HH; k += 256){
    float hv = bf2f(h[b * HH + k]);
    const float* wr = Wph + (size_t)k * 10;
    #pragma unroll
    for (int c = 0; c < 10; ++c) p[c] += hv * wr[c];
  }
  #pragma unroll
  for (int c = 0; c < 10; ++c) red[c][tid] = p[c];
  __syncthreads();
  for (int s = 128; s > 0; s >>= 1){
    if (tid < s){
      #pragma unroll
      for (int c = 0; c < 10; ++c) red[c][tid] += red[c][tid + s];
    }
    __syncthreads();
  }
  if (tid < 10) out[b * 10 + tid] = red[tid][0] + bp[tid];
}

extern "C" void kernel_launch(void* const* d_in, const int* in_sizes, int n_in,
                              void* d_out, int out_size, void* d_ws, size_t ws_size,
                              hipStream_t stream){
  (void)in_sizes; (void)n_in; (void)out_size; (void)ws_size;
  const float* x   = (const float*)d_in[0];
  const float* Wfx = (const float*)d_in[1];
  const float* Wix = (const float*)d_in[2];
  const float* Wgx = (const float*)d_in[3];
  const float* Wox = (const float*)d_in[4];
  const float* Wfh = (const float*)d_in[5];
  const float* Wih = (const float*)d_in[6];
  const float* Wgh = (const float*)d_in[7];
  const float* Woh = (const float*)d_in[8];
  const float* bfv = (const float*)d_in[9];
  const float* biv = (const float*)d_in[10];
  const float* bgv = (const float*)d_in[11];
  const float* bov = (const float*)d_in[12];
  const float* Wph = (const float*)d_in[13];
  const float* bp  = (const float*)d_in[14];

  char* ws = (char*)d_ws;
  u16*  Wpack = (u16*)ws;                    // 10,485,760 B
  u16*  xT    = (u16*)(ws + 10485760);       // 16,777,216 B
  u16*  h0    = (u16*)(ws + 27262976);       //    262,144 B
  u16*  h1    = (u16*)(ws + 27525120);       //    262,144 B
  float* cb   = (float*)(ws + 27787264);     //    524,288 B

  prep_wpack<<<2560, 256, 0, stream>>>(Wfx, Wix, Wgx, Wox, Wfh, Wih, Wgh, Woh, Wpack);
  prep_xT<<<4096, 256, 0, stream>>>(x, xT);
  hipMemsetAsync(h0, 0, 262144, stream);
  hipMemsetAsync(cb, 0, 524288, stream);

  for (int t = 0; t < TT; ++t){
    const u16* hin  = (t & 1) ? h1 : h0;
    u16*       hout = (t & 1) ? h0 : h1;
    lstm_step<<<dim3(64, 8), 512, 0, stream>>>(xT + (size_t)t * BB * DD, Wpack,
                                               hin, hout, cb, bfv, biv, bgv, bov);
  }
  // t=255 (odd) wrote h0 -> final hidden state lives in h0
  final_proj<<<128, 256, 0, stream>>>(h0, Wph, bp, (float*)d_out);
}

// Round 16
// 1715.521 us; speedup vs baseline: 1.0957x; 1.0957x over previous
//
#include <hip/hip_runtime.h>
#include <math.h>

// LSTM: B=128, T=256, D=256, H=1024, C=10
// Round 17: the CLEAN B-dedup test (R10/R12 were confounded).
//   R15 post-mortem: 2x512-thr blocks/CU = 1880us, worse than R14's single
//   1024-thr block (1757us): same waves/SIMD but doubled per-block staging
//   critical path + doubled per-wave B-loads beat the desync gain.
//   Remaining quantified term: B-fragment L2 BW. R14: 32 blocks/XCD x 320KB
//   = 10.2MB/step into ~4.3TB/s per-XCD L2 ~= 2.4us of the 6.5us step.
//   This round, ALL R14-proven elements kept (256 blocks, 1024 thr, 16
//   waves = 4 gates x 4 K-quarters, 20 MFMA/wave, staging slot formula,
//   swzb, pLds[4] single-phase combine, c-prefetch, fast-math) — only the
//   tile shape changes: block = 32 rows x 16 cols. Each wave feeds ONE
//   B-stream (ct = g*64 + bx) into TWO A-tiles: B-loads/wave halve (10),
//   MFMA/wave unchanged (20). Per-XCD: B 10.2->5.1MB, staging 1.3->2.6MB,
//   net -3.8MB ~= -0.9us/step.
//   Grid (64,4): id = bx + 64*by -> XCD = bx%8; the 4 by-blocks of each bx
//   share the B panel on one XCD's L2.
//   Staging: 5120 chunks = 5 exact rounds of 1024 thr; rows 0-15 -> AsLo,
//   16-31 -> AsHi (each the R13-proven 40KB layout). LDS 114.8KB.
//   VGPR ~100 < 128 cap (launch_bounds(1024,1)).
// Workspace layout (28,311,552 B total):
//   [0)          Wpack  bf16  10,485,760 B
//   [10485760)   xT     bf16  16,777,216 B   ([T][B][D], x transposed+cast)
//   [27262976)   h0     bf16     262,144 B
//   [27525120)   h1     bf16     262,144 B
//   [27787264)   c      fp32     524,288 B

#define BB 128
#define TT 256
#define DD 256
#define HH 1024
#define NKT 40   // 1280 / 32 k-tiles
#define KQT 10   // k-tiles per K-quarter wave
#define PFA 4    // A-fragment prefetch depth (per tile stream)
#define PFB 5    // B-fragment prefetch depth

typedef __bf16 bf16x8 __attribute__((ext_vector_type(8)));
typedef float  f32x4  __attribute__((ext_vector_type(4)));
typedef unsigned short u16;
typedef u16 u16x8 __attribute__((ext_vector_type(8)));

__device__ __forceinline__ u16 f2bf(float f){
  unsigned u = __builtin_bit_cast(unsigned, f);
  u += 0x7fffu + ((u >> 16) & 1u);            // round-to-nearest-even
  return (u16)(u >> 16);
}
__device__ __forceinline__ float bf2f(u16 b){
  unsigned u = ((unsigned)b) << 16;
  return __builtin_bit_cast(float, u);
}
__device__ __forceinline__ float sigm(float x){
  return 1.f / (1.f + __expf(-x));            // R3/R4/R11-proven numerics
}
__device__ __forceinline__ float tanh_fast(float x){
  return 2.f / (1.f + __expf(-2.f * x)) - 1.f;
}
// As slot bits (per 16-row tile): m=[0:3], q=[4:5], kt=[6:11]. R11-proven
// involution: staging wave's 8 consecutive lanes -> 8 distinct bank groups.
__device__ __forceinline__ int swzb(int slot){
  return slot ^ ((slot >> 6) & 7) ^ (((slot >> 4) & 3) << 1);
}

// ---- pack weights into MFMA B-fragment order -------------------------------
// Wpack[ct][kt][lane][j]: ct in [0,256) covers gate-cols [ct*16, ct*16+16)
// (col = gate*1024 + n); element = W[k = kt*32 + (lane>>4)*8 + j][col = ct*16 + (lane&15)]
__global__ void prep_wpack(const float* __restrict__ Wfx, const float* __restrict__ Wix,
                           const float* __restrict__ Wgx, const float* __restrict__ Wox,
                           const float* __restrict__ Wfh, const float* __restrict__ Wih,
                           const float* __restrict__ Wgh, const float* __restrict__ Woh,
                           u16* __restrict__ Wpack){
  int id = blockIdx.x * 256 + threadIdx.x;    // [0, 655360)
  int lane = id & 63;
  int kt = (id >> 6) % NKT;
  int ct = id / (64 * NKT);
  int col = ct * 16 + (lane & 15);
  int g = col >> 10, n = col & 1023;
  int kbase = kt * 32 + (lane >> 4) * 8;
  const float* Wx = (g==0) ? Wfx : (g==1) ? Wix : (g==2) ? Wgx : Wox;
  const float* Wh = (g==0) ? Wfh : (g==1) ? Wih : (g==2) ? Wgh : Woh;
  u16x8 v;
  #pragma unroll
  for (int j = 0; j < 8; ++j){
    int k = kbase + j;
    float f = (k < DD) ? Wx[k * HH + n] : Wh[(k - DD) * HH + n];
    v[j] = f2bf(f);
  }
  *(u16x8*)(Wpack + (size_t)id * 8) = v;      // dst index == id (by construction)
}

// ---- transpose+cast x: xT[t][b][d] = bf16(x[b][t][d]) ----------------------
__global__ void prep_xT(const float* __restrict__ x, u16* __restrict__ xT){
  int id = blockIdx.x * 256 + threadIdx.x;    // [0, 1048576), 8 elems each
  int t = id >> 12;
  int b = (id >> 5) & 127;
  int d0 = (id & 31) * 8;
  const float* src = x + ((size_t)b * TT + t) * DD + d0;
  u16x8 v;
  #pragma unroll
  for (int j = 0; j < 8; ++j) v[j] = f2bf(src[j]);
  *(u16x8*)(xT + (size_t)id * 8) = v;
}

// ---- one LSTM time step: GEMM (bf16 MFMA) + gate activations + state update
// Block: 32 rows x 16 cols x 4 gates, 1024 thr. Waves: g = w&3, kq = w>>2.
// Each wave: ONE B stream (10 kt), TWO 16-row A tiles -> 20 MFMAs.
__global__ __launch_bounds__(1024, 1) void lstm_step(
    const u16* __restrict__ xTt,   // [128][256] bf16 (t-slice of xT)
    const u16* __restrict__ Wpack,
    const u16* __restrict__ hin,   // [128][1024] bf16
    u16* __restrict__ hout,        // [128][1024] bf16
    float* __restrict__ cbuf,      // [128][1024] fp32
    const float* __restrict__ bfv, const float* __restrict__ biv,
    const float* __restrict__ bgv, const float* __restrict__ bov){
  __shared__ u16x8 AsLo[NKT * 64];    // 40 KB: rows 0..15, R13 layout+swzb
  __shared__ u16x8 AsHi[NKT * 64];    // 40 KB: rows 16..31
  __shared__ float pLds[4][32][68];   // per-K-quarter partials (34.8 KB)
  const int tid = threadIdx.x;
  const int bx = blockIdx.x;       // n-tile [0,64); XCD = bx%8
  const int n0 = bx * 16;          // hidden-unit tile (16 cols)
  const int m0 = blockIdx.y * 32;  // batch-row tile (32 rows)

  // cell-update ownership fixed by tid (tid<512) -> prefetch c-state NOW
  const int crow = tid >> 4, cnn = tid & 15;   // crow in [0,64) but used <32
  const int gi = (m0 + (crow & 31)) * HH + n0 + cnn;
  float cprev = 0.f;
  if (tid < 512) cprev = cbuf[gi];

  const int w = tid >> 6, lane = tid & 63, cr = lane & 15, q4 = lane >> 4;
  const int g  = w & 3;            // gate
  const int kq = w >> 2;           // K-quarter: kt in [kq*10, kq*10+10)
  const int ktBeg = kq * KQT;

  // ONE B fragment stream per wave: ct = g*64 + bx (gate g, cols n0..n0+15).
  // Prologue loads issued BEFORE staging so L2 latency hides under staging.
  const u16x8* wq = (const u16x8*)Wpack + (size_t)(g * 64 + bx) * NKT * 64 + lane;
  u16x8 bP[PFB];
  #pragma unroll
  for (int i = 0; i < PFB; ++i) bP[i] = wq[(size_t)(ktBeg + i) * 64];

  // Stage A = [x_t | h] for 32 rows: 5120 chunks = 5 exact rounds x 1024 thr.
  // chunk ch: tile = (ch>=2560 ? Hi : Lo); ch2 -> m = ch2/160, k0 = (ch2%160)*8
  // slot = kt*64 + 16*q + m (R13-proven), swzb.
  #pragma unroll
  for (int it = 0; it < 5; ++it){
    int ch = tid + it * 1024;
    int hi = (ch >= 2560) ? 1 : 0;
    int ch2 = ch - hi * 2560;
    int m = ch2 / 160;
    int k0 = (ch2 - m * 160) * 8;
    int row = m0 + hi * 16 + m;
    const u16* src = (k0 < DD) ? (xTt + row * DD + k0)
                               : (hin + row * HH + (k0 - DD));
    u16x8 val = *(const u16x8*)src;
    int kt = k0 >> 5, q = (k0 >> 3) & 3;
    int slot = swzb(kt * 64 + 16 * q + m);
    if (hi) AsHi[slot] = val; else AsLo[slot] = val;
  }
  __syncthreads();

  u16x8 aLoP[PFA], aHiP[PFA];
  #pragma unroll
  for (int i = 0; i < PFA; ++i){
    aLoP[i] = AsLo[swzb((ktBeg + i) * 64 + lane)];
    aHiP[i] = AsHi[swzb((ktBeg + i) * 64 + lane)];
  }

  f32x4 accLo = {0.f, 0.f, 0.f, 0.f}, accHi = {0.f, 0.f, 0.f, 0.f};
  #pragma unroll
  for (int kt = 0; kt < KQT; ++kt){
    u16x8 alo = aLoP[kt % PFA], ahi = aHiP[kt % PFA], b = bP[kt % PFB];
    if (kt + PFA < KQT){
      aLoP[kt % PFA] = AsLo[swzb((ktBeg + kt + PFA) * 64 + lane)];
      aHiP[kt % PFA] = AsHi[swzb((ktBeg + kt + PFA) * 64 + lane)];
    }
    if (kt + PFB < KQT)
      bP[kt % PFB] = wq[(size_t)(ktBeg + kt + PFB) * 64];
    accLo = __builtin_amdgcn_mfma_f32_16x16x32_bf16(__builtin_bit_cast(bf16x8, alo),
              __builtin_bit_cast(bf16x8, b), accLo, 0, 0, 0);
    accHi = __builtin_amdgcn_mfma_f32_16x16x32_bf16(__builtin_bit_cast(bf16x8, ahi),
              __builtin_bit_cast(bf16x8, b), accHi, 0, 0, 0);
  }

  // single-phase combine (R13/R14-proven): kq=0 adds bias, ONE barrier.
  // C/D layout: col = cr, local row = q4*4 + r; Hi tile rows +16.
  if (kq == 0){
    const float* bptr = (g==0) ? bfv : (g==1) ? biv : (g==2) ? bgv : bov;
    const float bias = bptr[n0 + cr];
    #pragma unroll
    for (int r = 0; r < 4; ++r){
      pLds[0][q4 * 4 + r][g * 16 + cr]      = accLo[r] + bias;
      pLds[0][16 + q4 * 4 + r][g * 16 + cr] = accHi[r] + bias;
    }
  } else {
    #pragma unroll
    for (int r = 0; r < 4; ++r){
      pLds[kq][q4 * 4 + r][g * 16 + cr]      = accLo[r];
      pLds[kq][16 + q4 * 4 + r][g * 16 + cr] = accHi[r];
    }
  }
  __syncthreads();

  // fused LSTM cell update: 512 (row, hidden) units, tid<512
  if (tid < 512){
    float fp = pLds[0][crow][cnn]      + pLds[1][crow][cnn]
             + pLds[2][crow][cnn]      + pLds[3][crow][cnn];
    float ip = pLds[0][crow][16 + cnn] + pLds[1][crow][16 + cnn]
             + pLds[2][crow][16 + cnn] + pLds[3][crow][16 + cnn];
    float gp = pLds[0][crow][32 + cnn] + pLds[1][crow][32 + cnn]
             + pLds[2][crow][32 + cnn] + pLds[3][crow][32 + cnn];
    float op = pLds[0][crow][48 + cnn] + pLds[1][crow][48 + cnn]
             + pLds[2][crow][48 + cnn] + pLds[3][crow][48 + cnn];
    float fs = sigm(fp);
    float is = sigm(ip);
    float gs = tanh_fast(gp);
    float os = sigm(op);
    float cn = gs * is + cprev * fs;
    cbuf[gi] = cn;
    hout[gi] = f2bf(tanh_fast(cn) * os);
  }
}

// ---- out[b][c] = h_T[b] . Wph[:,c] + bp[c] ---------------------------------
__global__ void final_proj(const u16* __restrict__ h, const float* __restrict__ Wph,
                           const float* __restrict__ bp, float* __restrict__ out){
  __shared__ float red[10][256];
  int b = blockIdx.x, tid = threadIdx.x;
  float p[10];
  #pragma unroll
  for (int c = 0; c < 10; ++c) p[c] = 0.f;
  for (int k = tid; k < HH; k += 256){
    float hv = bf2f(h[b * HH + k]);
    const float* wr = Wph + (size_t)k * 10;
    #pragma unroll
    for (int c = 0; c < 10; ++c) p[c] += hv * wr[c];
  }
  #pragma unroll
  for (int c = 0; c < 10; ++c) red[c][tid] = p[c];
  __syncthreads();
  for (int s = 128; s > 0; s >>= 1){
    if (tid < s){
      #pragma unroll
      for (int c = 0; c < 10; ++c) red[c][tid] += red[c][tid + s];
    }
    __syncthreads();
  }
  if (tid < 10) out[b * 10 + tid] = red[tid][0] + bp[tid];
}

extern "C" void kernel_launch(void* const* d_in, const int* in_sizes, int n_in,
                              void* d_out, int out_size, void* d_ws, size_t ws_size,
                              hipStream_t stream){
  (void)in_sizes; (void)n_in; (void)out_size; (void)ws_size;
  const float* x   = (const float*)d_in[0];
  const float* Wfx = (const float*)d_in[1];
  const float* Wix = (const float*)d_in[2];
  const float* Wgx = (const float*)d_in[3];
  const float* Wox = (const float*)d_in[4];
  const float* Wfh = (const float*)d_in[5];
  const float* Wih = (const float*)d_in[6];
  const float* Wgh = (const float*)d_in[7];
  const float* Woh = (const float*)d_in[8];
  const float* bfv = (const float*)d_in[9];
  const float* biv = (const float*)d_in[10];
  const float* bgv = (const float*)d_in[11];
  const float* bov = (const float*)d_in[12];
  const float* Wph = (const float*)d_in[13];
  const float* bp  = (const float*)d_in[14];

  char* ws = (char*)d_ws;
  u16*  Wpack = (u16*)ws;                    // 10,485,760 B
  u16*  xT    = (u16*)(ws + 10485760);       // 16,777,216 B
  u16*  h0    = (u16*)(ws + 27262976);       //    262,144 B
  u16*  h1    = (u16*)(ws + 27525120);       //    262,144 B
  float* cb   = (float*)(ws + 27787264);     //    524,288 B

  prep_wpack<<<2560, 256, 0, stream>>>(Wfx, Wix, Wgx, Wox, Wfh, Wih, Wgh, Woh, Wpack);
  prep_xT<<<4096, 256, 0, stream>>>(x, xT);
  hipMemsetAsync(h0, 0, 262144, stream);
  hipMemsetAsync(cb, 0, 524288, stream);

  for (int t = 0; t < TT; ++t){
    const u16* hin  = (t & 1) ? h1 : h0;
    u16*       hout = (t & 1) ? h0 : h1;
    lstm_step<<<dim3(64, 4), 1024, 0, stream>>>(xT + (size_t)t * BB * DD, Wpack,
                                                hin, hout, cb, bfv, biv, bgv, bov);
  }
  // t=255 (odd) wrote h0 -> final hidden state lives in h0
  final_proj<<<128, 256, 0, stream>>>(h0, Wph, bp, (float*)d_out);
}